// Round 2
// baseline (583.249 us; speedup 1.0000x reference)
//
#include <hip/hip_runtime.h>

typedef __attribute__((ext_vector_type(8))) short short8;
typedef __attribute__((ext_vector_type(4))) float f32x4;
typedef unsigned short ushort_t;
typedef unsigned int uint_t;

#define VOCAB 401
#define T_ 140
#define E_ 128
#define H_ 256
#define B_ 4096
#define HPAD 264  // shorts per hB row: 16B-aligned rows, 2-way LDS banks (free)

// Device-global scratch: avoids any dependence on ws_size (suspected overflow in R1).
__device__ int g_isbf16;
__device__ float Gf[VOCAB * 768];       // 1.23 MB, L2-resident gather table
__device__ ushort_t WhhB[768 * H_];     // canonical bf16 W_hh (384 KB)

__device__ __forceinline__ float bf2f(ushort_t u) {
  union { uint_t i; float f; } x; x.i = ((uint_t)u) << 16; return x.f;
}
__device__ __forceinline__ ushort_t f2bf(float f) {
  union { float f; uint_t i; } x; x.f = f;
  uint_t r = x.i + 0x7FFFu + ((x.i >> 16) & 1u);
  return (ushort_t)(r >> 16);
}
// Saturates correctly through +-inf (exp2->inf -> rcp->0), no clamps needed.
__device__ __forceinline__ float fast_sigmoid(float x) {
  return __builtin_amdgcn_rcpf(1.f + __builtin_amdgcn_exp2f(-1.442695041f * x));
}
__device__ __forceinline__ float fast_tanh(float x) {
  return 1.f - 2.f * __builtin_amdgcn_rcpf(1.f + __builtin_amdgcn_exp2f(2.885390082f * x));
}
// Dual-dtype scalar load (isb: buffer is bf16, else f32).
__device__ __forceinline__ float ldf(const void* p, size_t i, int isb) {
  return isb ? bf2f(((const ushort_t*)p)[i]) : ((const float*)p)[i];
}
__device__ __forceinline__ void ld8f(const void* p, size_t idx, int isb, float* o) {
  if (isb) {
    short8 v = *(const short8*)((const ushort_t*)p + idx);
#pragma unroll
    for (int e = 0; e < 8; ++e) o[e] = bf2f((ushort_t)v[e]);
  } else {
    f32x4 a = *(const f32x4*)((const float*)p + idx);
    f32x4 b = *(const f32x4*)((const float*)p + idx + 4);
#pragma unroll
    for (int e = 0; e < 4; ++e) { o[e] = a[e]; o[4 + e] = b[e]; }
  }
}

// ---------------------------------------------------------------------------
// Kernel 0: dtype probe. Even-position shorts of embed (N(0,1) values):
// bf16 data -> exponent field in [100,140] ~always; f32 data -> low-mantissa
// shorts, exponent ~uniform -> ~10/64 sane. Threshold 40.
// ---------------------------------------------------------------------------
__global__ void detect_dtype(const ushort_t* __restrict__ embed_raw) {
  int lane = threadIdx.x;  // 64 threads
  ushort_t s = embed_raw[2 * lane];
  int e = (s >> 7) & 0xFF;
  unsigned long long m = __ballot(e >= 100 && e <= 140);
  if (lane == 0) g_isbf16 = (__popcll(m) >= 40) ? 1 : 0;
}

// ---------------------------------------------------------------------------
// Kernel 1: canonicalize W_hh to bf16 (bit-copy if already bf16).
// ---------------------------------------------------------------------------
__global__ void canon_whh(const void* __restrict__ W_hh) {
  int isb = g_isbf16;
  int i4 = (blockIdx.x * 256 + threadIdx.x) * 4;  // grid 192 -> covers 768*256
  if (isb) {
    *(uint2*)&WhhB[i4] = *(const uint2*)((const ushort_t*)W_hh + i4);
  } else {
    f32x4 v = *(const f32x4*)((const float*)W_hh + i4);
    uint_t p0 = (uint_t)f2bf(v[0]) | ((uint_t)f2bf(v[1]) << 16);
    uint_t p1 = (uint_t)f2bf(v[2]) | ((uint_t)f2bf(v[3]) << 16);
    uint2 pk; pk.x = p0; pk.y = p1;
    *(uint2*)&WhhB[i4] = pk;
  }
}

// ---------------------------------------------------------------------------
// Kernel 2: G[v][row] = dot(embed[v], W_ih[row]) + b_ih[row] + (row<512 ? b_hh[row] : 0)
// Collapses the entire input-side projection into a 401x768 table.
// ---------------------------------------------------------------------------
__global__ void build_G(const void* __restrict__ embed,
                        const void* __restrict__ W_ih,
                        const void* __restrict__ b_ih,
                        const void* __restrict__ b_hh) {
  __shared__ float emb[E_];
  const int isb = g_isbf16;
  const int v = blockIdx.x, g = blockIdx.y, j = threadIdx.x;  // 256 threads
  if (j < E_) emb[j] = ldf(embed, (size_t)v * E_ + j, isb);
  __syncthreads();
  const int row = g * H_ + j;
  float s = 0.f;
#pragma unroll
  for (int k8 = 0; k8 < E_ / 8; ++k8) {
    float wv[8];
    ld8f(W_ih, (size_t)row * E_ + k8 * 8, isb, wv);
#pragma unroll
    for (int e = 0; e < 8; ++e) s += emb[k8 * 8 + e] * wv[e];
  }
  s += ldf(b_ih, row, isb);
  if (g < 2) s += ldf(b_hh, row, isb);
  Gf[v * 768 + row] = s;
}

// ---------------------------------------------------------------------------
// Kernel 3: persistent GRU. 256 WGs x 1024 threads; WG owns 16 batch rows.
// W_hh register-resident (wave w owns unit-triplet rows -> 24 A-frags = 96 VGPRs).
// h: bf16 double-buffer in LDS (MFMA B operand) + f32 in registers (C-layout).
// One barrier per step.
// ---------------------------------------------------------------------------
__launch_bounds__(1024)
__global__ void gru_persist(const int* __restrict__ input,
                            const void* __restrict__ hidden,
                            const void* __restrict__ b_hh,
                            const void* __restrict__ W_out,
                            const void* __restrict__ b_out,
                            void* __restrict__ out) {
  __shared__ ushort_t hB[2][16 * HPAD];
  __shared__ float bhhn[H_];
  __shared__ int ids[16 * T_];

  const int isb  = g_isbf16;
  const int tid  = threadIdx.x;
  const int w    = tid >> 6;        // wave 0..15
  const int lane = tid & 63;
  const int quad = lane >> 4;
  const int col  = lane & 15;       // batch column (B-operand n / C col / ids row)
  const int wg   = blockIdx.x;
  const int u0   = w << 4;
  const int u0q  = u0 + (quad << 2);

  // ---- stage h0 into hB[0] ----
  if (tid < 512) {
    int r = tid >> 5, c0 = (tid & 31) << 3;
    size_t gi = (size_t)(wg * 16 + r) * H_ + c0;
    ushort_t* dst = &hB[0][r * HPAD + c0];
    if (isb) {
      *(short8*)dst = *(const short8*)((const ushort_t*)hidden + gi);
    } else {
      float tmp[8];
      ld8f(hidden, gi, 0, tmp);
#pragma unroll
      for (int e = 0; e < 8; ++e) dst[e] = f2bf(tmp[e]);
    }
  }
  if (tid < H_) bhhn[tid] = ldf(b_hh, 512 + tid, isb);
  // ---- stage this WG's input ids (contiguous rows wg*16..wg*16+15) ----
  for (int k = tid; k < 16 * T_; k += 1024)
    ids[k] = input[(size_t)wg * 16 * T_ + k];

  // ---- persistent W_hh fragments: A[m=lane&15][k=quad*8+j], rows g*256+u0+col ----
  short8 wA[3][8];
#pragma unroll
  for (int g = 0; g < 3; ++g) {
    const ushort_t* wrow = WhhB + (size_t)(g * H_ + u0 + col) * H_ + (quad << 3);
#pragma unroll
    for (int kt = 0; kt < 8; ++kt) wA[g][kt] = *(const short8*)(wrow + kt * 32);
  }

  __syncthreads();

  // f32 state in registers, C-layout: unit = u0 + quad*4 + i, batch = col
  float hreg[4];
#pragma unroll
  for (int i = 0; i < 4; ++i)
    hreg[i] = bf2f(hB[0][col * HPAD + u0q + i]);

  const int idbase = col * T_;

  for (int t = 0; t < T_; ++t) {
    const int cur = t & 1;
    const int nxt = cur ^ 1;
    const ushort_t* hr = &hB[cur][col * HPAD + (quad << 3)];

    int v = ids[idbase + t];  // LDS broadcast, 2-way banks (free)

    f32x4 accr = {0.f, 0.f, 0.f, 0.f};
    f32x4 accz = {0.f, 0.f, 0.f, 0.f};
    f32x4 accn = {0.f, 0.f, 0.f, 0.f};
#pragma unroll
    for (int kt = 0; kt < 8; ++kt) {
      short8 b = *(const short8*)(hr + kt * 32);  // B[k=kt*32+quad*8+j][n=col]
      accr = __builtin_amdgcn_mfma_f32_16x16x32_bf16(wA[0][kt], b, accr, 0, 0, 0);
      accz = __builtin_amdgcn_mfma_f32_16x16x32_bf16(wA[1][kt], b, accz, 0, 0, 0);
      accn = __builtin_amdgcn_mfma_f32_16x16x32_bf16(wA[2][kt], b, accn, 0, 0, 0);
    }

    // gi gather from G-table (L2-resident), in C-layout positions
    const float* gp = Gf + v * 768 + u0q;
    f32x4 gir = *(const f32x4*)gp;
    f32x4 giz = *(const f32x4*)(gp + H_);

    float r_[4], z_[4];
#pragma unroll
    for (int i = 0; i < 4; ++i) {
      r_[i] = fast_sigmoid(gir[i] + accr[i]);
      z_[i] = fast_sigmoid(giz[i] + accz[i]);
    }

    f32x4 gin = *(const f32x4*)(gp + 2 * H_);
    f32x4 bh  = *(const f32x4*)&bhhn[u0q];

    ushort_t* hw = &hB[nxt][col * HPAD + u0q];
    uint_t pk[2];
#pragma unroll
    for (int i = 0; i < 4; ++i) {
      float hn = accn[i] + bh[i];             // h_n (b_hh_n inside, multiplied by r)
      float n  = fast_tanh(gin[i] + r_[i] * hn);
      float h  = n + z_[i] * (hreg[i] - n);   // (1-z)*n + z*h
      hreg[i] = h;
      ushort_t hb = f2bf(h);
      if (i & 1) pk[i >> 1] |= ((uint_t)hb) << 16;
      else       pk[i >> 1]  = hb;
    }
    *(uint_t*)&hw[0] = pk[0];
    *(uint_t*)&hw[2] = pk[1];

    __syncthreads();
  }

  // ---- epilogue: logits + log_softmax; wave w handles local batch w ----
  // final h is in hB[0] (T=140 even)
  {
    const ushort_t* hrow = &hB[0][w * HPAD + (lane << 2)];
    float h0 = bf2f(hrow[0]), h1 = bf2f(hrow[1]), h2 = bf2f(hrow[2]), h3 = bf2f(hrow[3]);
    float d[3];
#pragma unroll
    for (int o = 0; o < 3; ++o) {
      size_t base = (size_t)o * H_ + (lane << 2);
      d[o] = ldf(W_out, base, isb) * h0 + ldf(W_out, base + 1, isb) * h1 +
             ldf(W_out, base + 2, isb) * h2 + ldf(W_out, base + 3, isb) * h3;
      for (int off = 1; off < 64; off <<= 1) d[o] += __shfl_xor(d[o], off);
    }
    if (lane == 0) {
      float l0 = d[0] + ldf(b_out, 0, isb);
      float l1 = d[1] + ldf(b_out, 1, isb);
      float l2 = d[2] + ldf(b_out, 2, isb);
      float m = fmaxf(l0, fmaxf(l1, l2));
      float s = __builtin_amdgcn_exp2f((l0 - m) * 1.442695041f) +
                __builtin_amdgcn_exp2f((l1 - m) * 1.442695041f) +
                __builtin_amdgcn_exp2f((l2 - m) * 1.442695041f);
      float ls = __builtin_amdgcn_logf(s) * 0.6931471806f;
      size_t ob = (size_t)(wg * 16 + w) * 3;
      float o0 = l0 - m - ls, o1 = l1 - m - ls, o2 = l2 - m - ls;
      if (isb) {
        ushort_t* ob16 = (ushort_t*)out;
        ob16[ob] = f2bf(o0); ob16[ob + 1] = f2bf(o1); ob16[ob + 2] = f2bf(o2);
      } else {
        float* of = (float*)out;
        of[ob] = o0; of[ob + 1] = o1; of[ob + 2] = o2;
      }
    }
  }
  // ---- h_final copy, coalesced ----
  {
    int e = tid << 2;
    int bb = e >> 8, uu = e & 255;
    const ushort_t* src = &hB[0][bb * HPAD + uu];
    size_t oi = 12288 + (size_t)wg * 4096 + e;
    if (isb) {
      *(uint2*)((ushort_t*)out + oi) = *(const uint2*)src;
    } else {
      float* of = (float*)out;
      of[oi] = bf2f(src[0]); of[oi + 1] = bf2f(src[1]);
      of[oi + 2] = bf2f(src[2]); of[oi + 3] = bf2f(src[3]);
    }
  }
}

extern "C" void kernel_launch(void* const* d_in, const int* in_sizes, int n_in,
                              void* d_out, int out_size, void* d_ws, size_t ws_size,
                              hipStream_t stream) {
  (void)in_sizes; (void)n_in; (void)out_size; (void)d_ws; (void)ws_size;
  const int* input = (const int*)d_in[0];
  const void* hidden = d_in[1];
  const void* embed  = d_in[2];
  const void* W_ih   = d_in[3];
  const void* W_hh   = d_in[4];
  const void* b_ih   = d_in[5];
  const void* b_hh   = d_in[6];
  const void* W_out  = d_in[7];
  const void* b_out  = d_in[8];

  detect_dtype<<<1, 64, 0, stream>>>((const ushort_t*)embed);
  canon_whh<<<192, 256, 0, stream>>>(W_hh);
  build_G<<<dim3(VOCAB, 3), 256, 0, stream>>>(embed, W_ih, b_ih, b_hh);
  gru_persist<<<B_ / 16, 1024, 0, stream>>>(input, hidden, b_hh, W_out, b_out, d_out);
}

// Round 3
// 435.004 us; speedup vs baseline: 1.3408x; 1.3408x over previous
//
#include <hip/hip_runtime.h>

typedef __attribute__((ext_vector_type(8))) short short8;
typedef __attribute__((ext_vector_type(4))) float f32x4;
typedef unsigned short ushort_t;
typedef unsigned int uint_t;

#define VOCAB 401
#define T_ 140
#define E_ 128
#define H_ 256
#define B_ 4096
#define HPAD 264  // shorts per hB row: 16B-aligned rows

// Device-global scratch (no d_ws dependence). Rewritten fully every launch.
__device__ float Gf[VOCAB * 768];       // gi gather table (b_ih + b_hh folded for r,z)
__device__ ushort_t WhhB[768 * H_];     // canonical bf16 W_hh

__device__ __forceinline__ float bf2f(ushort_t u) {
  union { uint_t i; float f; } x; x.i = ((uint_t)u) << 16; return x.f;
}
__device__ __forceinline__ ushort_t f2bf(float f) {
  union { float f; uint_t i; } x; x.f = f;
  uint_t r = x.i + 0x7FFFu + ((x.i >> 16) & 1u);
  return (ushort_t)(r >> 16);
}
// Saturate correctly through +-inf; no clamps needed.
__device__ __forceinline__ float fast_sigmoid(float x) {
  return __builtin_amdgcn_rcpf(1.f + __builtin_amdgcn_exp2f(-1.442695041f * x));
}
__device__ __forceinline__ float fast_tanh(float x) {
  return 1.f - 2.f * __builtin_amdgcn_rcpf(1.f + __builtin_amdgcn_exp2f(2.885390082f * x));
}
__device__ __forceinline__ float ldf(const void* p, size_t i, int isb) {
  return isb ? bf2f(((const ushort_t*)p)[i]) : ((const float*)p)[i];
}
__device__ __forceinline__ void ld8f(const void* p, size_t idx, int isb, float* o) {
  if (isb) {
    short8 v = *(const short8*)((const ushort_t*)p + idx);
#pragma unroll
    for (int e = 0; e < 8; ++e) o[e] = bf2f((ushort_t)v[e]);
  } else {
    f32x4 a = *(const f32x4*)((const float*)p + idx);
    f32x4 b = *(const f32x4*)((const float*)p + idx + 4);
#pragma unroll
    for (int e = 0; e < 4; ++e) { o[e] = a[e]; o[4 + e] = b[e]; }
  }
}
// In-block dtype probe (wave 0): bf16 N(0,1) data -> sane exponent ~64/64;
// f32 low-mantissa shorts -> ~10/64. Threshold 40. Replaces a kernel launch.
__device__ __forceinline__ int block_probe_isbf16(const ushort_t* embed_raw, int* s) {
  if (threadIdx.x < 64) {
    ushort_t v = embed_raw[2 * threadIdx.x];
    int e = (v >> 7) & 0xFF;
    unsigned long long m = __ballot(e >= 100 && e <= 140);
    if (threadIdx.x == 0) *s = (__popcll(m) >= 40) ? 1 : 0;
  }
  __syncthreads();
  return *s;
}

// ---------------------------------------------------------------------------
// Canonicalize W_hh to bf16.
// ---------------------------------------------------------------------------
__global__ void canon_whh(const void* __restrict__ W_hh, const ushort_t* __restrict__ embed_raw) {
  __shared__ int sISB;
  int isb = block_probe_isbf16(embed_raw, &sISB);
  int i4 = (blockIdx.x * 256 + threadIdx.x) * 4;  // grid 192 covers 768*256
  if (isb) {
    *(uint2*)&WhhB[i4] = *(const uint2*)((const ushort_t*)W_hh + i4);
  } else {
    f32x4 v = *(const f32x4*)((const float*)W_hh + i4);
    uint2 pk;
    pk.x = (uint_t)f2bf(v[0]) | ((uint_t)f2bf(v[1]) << 16);
    pk.y = (uint_t)f2bf(v[2]) | ((uint_t)f2bf(v[3]) << 16);
    *(uint2*)&WhhB[i4] = pk;
  }
}

// ---------------------------------------------------------------------------
// G[v][row] = dot(embed[v], W_ih[row]) + b_ih[row] + (row<512 ? b_hh[row] : 0)
// ---------------------------------------------------------------------------
__global__ void build_G(const void* __restrict__ embed,
                        const void* __restrict__ W_ih,
                        const void* __restrict__ b_ih,
                        const void* __restrict__ b_hh) {
  __shared__ float emb[E_];
  __shared__ int sISB;
  const int isb = block_probe_isbf16((const ushort_t*)embed, &sISB);
  const int v = blockIdx.x, g = blockIdx.y, j = threadIdx.x;  // 256 threads
  if (j < E_) emb[j] = ldf(embed, (size_t)v * E_ + j, isb);
  __syncthreads();
  const int row = g * H_ + j;
  float s = 0.f;
#pragma unroll
  for (int k8 = 0; k8 < E_ / 8; ++k8) {
    float wv[8];
    ld8f(W_ih, (size_t)row * E_ + k8 * 8, isb, wv);
#pragma unroll
    for (int e = 0; e < 8; ++e) s += emb[k8 * 8 + e] * wv[e];
  }
  s += ldf(b_ih, row, isb);
  if (g < 2) s += ldf(b_hh, row, isb);
  Gf[v * 768 + row] = s;
}

// ---------------------------------------------------------------------------
// Persistent GRU. 256 WGs x 1024 threads; WG owns 16 batch rows.
// W_hh register/AGPR-resident (96 regs/wave). h double-buffered bf16 in LDS
// (MFMA B) + f32 in registers (C-layout). One barrier/step.
// R3: gi_r/gi_z folded into MFMA C-operand; G rows for t+1 prefetched
// pre-barrier into the dead acc registers; ids pre-scaled to byte offsets;
// v_perm bf16 pack.
// ---------------------------------------------------------------------------
__launch_bounds__(1024)
__global__ void gru_persist(const int* __restrict__ input,
                            const void* __restrict__ hidden,
                            const void* __restrict__ b_hh,
                            const void* __restrict__ W_out,
                            const void* __restrict__ b_out,
                            const ushort_t* __restrict__ embed_raw,
                            void* __restrict__ out) {
  __shared__ ushort_t hB[2][16 * HPAD];
  __shared__ float bhhn[H_];
  __shared__ int ids[16 * T_];
  __shared__ int sISB;

  const int isb  = block_probe_isbf16(embed_raw, &sISB);
  const int tid  = threadIdx.x;
  const int w    = tid >> 6;
  const int lane = tid & 63;
  const int quad = lane >> 4;
  const int col  = lane & 15;
  const int wg   = blockIdx.x;
  const int u0   = w << 4;
  const int u0q  = u0 + (quad << 2);

  // ---- stage h0 ----
  if (tid < 512) {
    int r = tid >> 5, c0 = (tid & 31) << 3;
    size_t gi = (size_t)(wg * 16 + r) * H_ + c0;
    ushort_t* dst = &hB[0][r * HPAD + c0];
    if (isb) {
      *(short8*)dst = *(const short8*)((const ushort_t*)hidden + gi);
    } else {
      float tmp[8];
      ld8f(hidden, gi, 0, tmp);
#pragma unroll
      for (int e = 0; e < 8; ++e) dst[e] = f2bf(tmp[e]);
    }
  }
  if (tid < H_) bhhn[tid] = ldf(b_hh, 512 + tid, isb);
  // ids as pre-scaled byte offsets into Gf
  for (int k = tid; k < 16 * T_; k += 1024)
    ids[k] = input[(size_t)wg * 16 * T_ + k] * 3072;

  // ---- persistent W_hh fragments: A[m=lane&15][k=quad*8+j] ----
  short8 wA[3][8];
#pragma unroll
  for (int g = 0; g < 3; ++g) {
    const ushort_t* wrow = WhhB + (size_t)(g * H_ + u0 + col) * H_ + (quad << 3);
#pragma unroll
    for (int kt = 0; kt < 8; ++kt) wA[g][kt] = *(const short8*)(wrow + kt * 32);
  }

  __syncthreads();

  float hreg[4];
#pragma unroll
  for (int i = 0; i < 4; ++i)
    hreg[i] = bf2f(hB[0][col * HPAD + u0q + i]);

  const int idbase = col * T_;
  const char* gB = (const char*)Gf + (size_t)u0q * 4;

  // preload G rows for t=0 directly into acc (C-layout!) / gin
  f32x4 accr, accz, gin;
  {
    int goff = ids[idbase];
    accr = *(const f32x4*)(gB + goff);
    accz = *(const f32x4*)(gB + goff + H_ * 4);
    gin  = *(const f32x4*)(gB + goff + 2 * H_ * 4);
  }

  for (int t = 0; t < T_; ++t) {
    const int cur = t & 1;
    const int nxt = cur ^ 1;
    const ushort_t* hr = &hB[cur][col * HPAD + (quad << 3)];

    f32x4 an = {0.f, 0.f, 0.f, 0.f};  // n-gate C must be 0 (gi_n stays outside r*)
#pragma unroll
    for (int kt = 0; kt < 8; ++kt) {
      short8 b = *(const short8*)(hr + kt * 32);  // B[k=kt*32+quad*8+j][n=col]
      accr = __builtin_amdgcn_mfma_f32_16x16x32_bf16(wA[0][kt], b, accr, 0, 0, 0);
      accz = __builtin_amdgcn_mfma_f32_16x16x32_bf16(wA[1][kt], b, accz, 0, 0, 0);
      an   = __builtin_amdgcn_mfma_f32_16x16x32_bf16(wA[2][kt], b, an,   0, 0, 0);
    }

    // next-step id read early (LDS latency hides under gate math)
    int tn = t + 1; if (tn == T_) tn = 0;
    int goff2 = ids[idbase + tn];

    f32x4 bh = *(const f32x4*)&bhhn[u0q];  // broadcast, conflict-free

    uint_t rr[4];
#pragma unroll
    for (int i = 0; i < 4; ++i) {
      float r_ = fast_sigmoid(accr[i]);
      float z_ = fast_sigmoid(accz[i]);
      float hn = an[i] + bh[i];
      float n  = fast_tanh(gin[i] + r_ * hn);
      float h  = n + z_ * (hreg[i] - n);
      hreg[i] = h;
      union { float f; uint_t u; } c; c.f = h;
      rr[i] = c.u + 0x7FFFu + ((c.u >> 16) & 1u);  // rounded; take high16
    }
    ushort_t* hw = &hB[nxt][col * HPAD + u0q];
    *(uint_t*)&hw[0] = __builtin_amdgcn_perm(rr[1], rr[0], 0x07060302);
    *(uint_t*)&hw[2] = __builtin_amdgcn_perm(rr[3], rr[2], 0x07060302);

    // prefetch G rows for t+1 into the (now dead) acc registers, pre-barrier
    accr = *(const f32x4*)(gB + goff2);
    accz = *(const f32x4*)(gB + goff2 + H_ * 4);
    gin  = *(const f32x4*)(gB + goff2 + 2 * H_ * 4);

    __syncthreads();
  }

  // ---- epilogue: logits + log_softmax; wave w handles local batch w ----
  {
    const ushort_t* hrow = &hB[0][w * HPAD + (lane << 2)];
    float h0 = bf2f(hrow[0]), h1 = bf2f(hrow[1]), h2 = bf2f(hrow[2]), h3 = bf2f(hrow[3]);
    float d[3];
#pragma unroll
    for (int o = 0; o < 3; ++o) {
      size_t base = (size_t)o * H_ + (lane << 2);
      d[o] = ldf(W_out, base, isb) * h0 + ldf(W_out, base + 1, isb) * h1 +
             ldf(W_out, base + 2, isb) * h2 + ldf(W_out, base + 3, isb) * h3;
      for (int off = 1; off < 64; off <<= 1) d[o] += __shfl_xor(d[o], off);
    }
    if (lane == 0) {
      float l0 = d[0] + ldf(b_out, 0, isb);
      float l1 = d[1] + ldf(b_out, 1, isb);
      float l2 = d[2] + ldf(b_out, 2, isb);
      float m = fmaxf(l0, fmaxf(l1, l2));
      float s = __builtin_amdgcn_exp2f((l0 - m) * 1.442695041f) +
                __builtin_amdgcn_exp2f((l1 - m) * 1.442695041f) +
                __builtin_amdgcn_exp2f((l2 - m) * 1.442695041f);
      float ls = __builtin_amdgcn_logf(s) * 0.6931471806f;
      size_t ob = (size_t)(wg * 16 + w) * 3;
      float o0 = l0 - m - ls, o1 = l1 - m - ls, o2 = l2 - m - ls;
      if (isb) {
        ushort_t* ob16 = (ushort_t*)out;
        ob16[ob] = f2bf(o0); ob16[ob + 1] = f2bf(o1); ob16[ob + 2] = f2bf(o2);
      } else {
        float* of = (float*)out;
        of[ob] = o0; of[ob + 1] = o1; of[ob + 2] = o2;
      }
    }
  }
  // ---- h_final copy, coalesced ----
  {
    int e = tid << 2;
    int bb = e >> 8, uu = e & 255;
    const ushort_t* src = &hB[0][bb * HPAD + uu];
    size_t oi = 12288 + (size_t)wg * 4096 + e;
    if (isb) {
      *(uint2*)((ushort_t*)out + oi) = *(const uint2*)src;
    } else {
      float* of = (float*)out;
      of[oi] = bf2f(src[0]); of[oi + 1] = bf2f(src[1]);
      of[oi + 2] = bf2f(src[2]); of[oi + 3] = bf2f(src[3]);
    }
  }
}

extern "C" void kernel_launch(void* const* d_in, const int* in_sizes, int n_in,
                              void* d_out, int out_size, void* d_ws, size_t ws_size,
                              hipStream_t stream) {
  (void)in_sizes; (void)n_in; (void)out_size; (void)d_ws; (void)ws_size;
  const int* input = (const int*)d_in[0];
  const void* hidden = d_in[1];
  const void* embed  = d_in[2];
  const void* W_ih   = d_in[3];
  const void* W_hh   = d_in[4];
  const void* b_hh   = d_in[6];
  const void* W_out  = d_in[7];
  const void* b_out  = d_in[8];
  const void* b_ih   = d_in[5];

  canon_whh<<<192, 256, 0, stream>>>(W_hh, (const ushort_t*)embed);
  build_G<<<dim3(VOCAB, 3), 256, 0, stream>>>(embed, W_ih, b_ih, b_hh);
  gru_persist<<<B_ / 16, 1024, 0, stream>>>(input, hidden, b_hh, W_out, b_out,
                                            (const ushort_t*)embed, d_out);
}